// Round 1
// baseline (83.214 us; speedup 1.0000x reference)
//
#include <hip/hip_runtime.h>

// Adaptive avg pool 8x224x224x256 NHWC fp32 -> 8x7x7x256.
// 224/7 = 32 exactly => uniform 32x32 windows, each output = mean of 1024 pixels.

constexpr int B  = 8;
constexpr int H  = 224;
constexpr int W  = 224;
constexpr int C  = 256;
constexpr int OH = 7;
constexpr int OW = 7;
constexpr int WIN = 32;          // window size in both dims
constexpr int CHUNKS = 8;        // row-chunks per window
constexpr int ROWS_PER_CHUNK = WIN / CHUNKS;   // 4
constexpr int G  = C / 4;        // 64 float4 channel groups
constexpr int OUT_ELEMS = B * OH * OW * C;     // 100352

__global__ void zero_out_kernel(float* __restrict__ out, int n) {
    int i = blockIdx.x * blockDim.x + threadIdx.x;
    if (i < n) out[i] = 0.0f;
}

__global__ __launch_bounds__(256) void pool_kernel(const float* __restrict__ x,
                                                   float* __restrict__ out) {
    // blockIdx.x in [0, B*OH*OW*CHUNKS)
    int bid   = blockIdx.x;
    int chunk = bid & (CHUNKS - 1);
    int t     = bid >> 3;
    int ow    = t % OW; t /= OW;
    int oh    = t % OH; t /= OH;
    int b     = t;

    int tid = threadIdx.x;
    int g   = tid & (G - 1);      // float4 channel group, 0..63
    int r   = tid >> 6;           // row within chunk, 0..3

    int row  = oh * WIN + chunk * ROWS_PER_CHUNK + r;
    int col0 = ow * WIN;

    const float4* p = reinterpret_cast<const float4*>(
        x + (((size_t)b * H + row) * W + col0) * C) + g;

    float4 acc = make_float4(0.f, 0.f, 0.f, 0.f);
#pragma unroll
    for (int c = 0; c < WIN; ++c) {
        float4 v = p[(size_t)c * G];   // stride 1 KiB between columns
        acc.x += v.x; acc.y += v.y; acc.z += v.z; acc.w += v.w;
    }

    __shared__ float4 lds[ROWS_PER_CHUNK][G];
    lds[r][g] = acc;
    __syncthreads();

    if (r == 0) {
        float4 a0 = lds[0][g];
        float4 a1 = lds[1][g];
        float4 a2 = lds[2][g];
        float4 a3 = lds[3][g];
        const float s = 1.0f / (float)(WIN * WIN);
        float* o = out + (((size_t)b * OH + oh) * OW + ow) * C + g * 4;
        atomicAdd(o + 0, (a0.x + a1.x + a2.x + a3.x) * s);
        atomicAdd(o + 1, (a0.y + a1.y + a2.y + a3.y) * s);
        atomicAdd(o + 2, (a0.z + a1.z + a2.z + a3.z) * s);
        atomicAdd(o + 3, (a0.w + a1.w + a2.w + a3.w) * s);
    }
}

extern "C" void kernel_launch(void* const* d_in, const int* in_sizes, int n_in,
                              void* d_out, int out_size, void* d_ws, size_t ws_size,
                              hipStream_t stream) {
    const float* x = (const float*)d_in[0];
    float* out = (float*)d_out;

    // d_out is poisoned; zero it before accumulation (every call — deterministic).
    zero_out_kernel<<<(OUT_ELEMS + 255) / 256, 256, 0, stream>>>(out, OUT_ELEMS);

    int nblocks = B * OH * OW * CHUNKS;   // 3136
    pool_kernel<<<nblocks, 256, 0, stream>>>(x, out);
}

// Round 2
// 78.245 us; speedup vs baseline: 1.0635x; 1.0635x over previous
//
#include <hip/hip_runtime.h>

// Adaptive avg pool 8x224x224x256 NHWC fp32 -> 8x7x7x256.
// 224/7 = 32 exactly => uniform 32x32 windows, each output = mean of 1024 pixels.
// Two-phase: (1) per-chunk partial sums -> d_ws (plain stores, no atomics),
//            (2) reduce 8 partials per output site -> d_out.

constexpr int B  = 8;
constexpr int H  = 224;
constexpr int W  = 224;
constexpr int C  = 256;
constexpr int OH = 7;
constexpr int OW = 7;
constexpr int WIN = 32;          // window size in both dims
constexpr int CHUNKS = 8;        // row-chunks per window
constexpr int ROWS_PER_CHUNK = WIN / CHUNKS;   // 4
constexpr int G  = C / 4;        // 64 float4 channel groups
constexpr int OUT_ELEMS = B * OH * OW * C;     // 100352
constexpr int NCHUNK_BLOCKS = B * OH * OW * CHUNKS;  // 3136
constexpr size_t WS_NEEDED = (size_t)NCHUNK_BLOCKS * C * sizeof(float);  // 3.2 MB

__global__ __launch_bounds__(256) void pool_partial_kernel(const float* __restrict__ x,
                                                           float* __restrict__ ws) {
    int bid   = blockIdx.x;
    int chunk = bid & (CHUNKS - 1);
    int t     = bid >> 3;
    int ow    = t % OW; t /= OW;
    int oh    = t % OH; t /= OH;
    int b     = t;

    int tid = threadIdx.x;
    int g   = tid & (G - 1);      // float4 channel group, 0..63
    int r   = tid >> 6;           // row within chunk, 0..3

    int row  = oh * WIN + chunk * ROWS_PER_CHUNK + r;
    int col0 = ow * WIN;

    const float4* p = reinterpret_cast<const float4*>(
        x + (((size_t)b * H + row) * W + col0) * C) + g;

    float4 acc = make_float4(0.f, 0.f, 0.f, 0.f);
#pragma unroll
    for (int c = 0; c < WIN; ++c) {
        float4 v = p[(size_t)c * G];   // wave reads 1 KiB contiguous per iter
        acc.x += v.x; acc.y += v.y; acc.z += v.z; acc.w += v.w;
    }

    __shared__ float4 lds[ROWS_PER_CHUNK][G];
    lds[r][g] = acc;
    __syncthreads();

    if (r == 0) {
        float4 a0 = lds[0][g];
        float4 a1 = lds[1][g];
        float4 a2 = lds[2][g];
        float4 a3 = lds[3][g];
        float4 s;
        s.x = a0.x + a1.x + a2.x + a3.x;
        s.y = a0.y + a1.y + a2.y + a3.y;
        s.z = a0.z + a1.z + a2.z + a3.z;
        s.w = a0.w + a1.w + a2.w + a3.w;
        reinterpret_cast<float4*>(ws)[(size_t)bid * G + g] = s;  // contiguous 1 KiB/block
    }
}

__global__ __launch_bounds__(256) void reduce_kernel(const float* __restrict__ ws,
                                                     float* __restrict__ out) {
    int i = blockIdx.x * 256 + threadIdx.x;   // output element id
    if (i >= OUT_ELEMS) return;
    int o = i >> 8;           // output site (b,oh,ow), matches pool's bid>>3 order
    int c = i & (C - 1);
    const float* p = ws + (size_t)(o * CHUNKS) * C + c;
    float s = 0.f;
#pragma unroll
    for (int k = 0; k < CHUNKS; ++k) s += p[(size_t)k * C];
    out[i] = s * (1.0f / (float)(WIN * WIN));
}

// ---- fallback (atomic) path, used only if ws_size is unexpectedly small ----
__global__ void zero_out_kernel(float* __restrict__ out, int n) {
    int i = blockIdx.x * blockDim.x + threadIdx.x;
    if (i < n) out[i] = 0.0f;
}

__global__ __launch_bounds__(256) void pool_atomic_kernel(const float* __restrict__ x,
                                                          float* __restrict__ out) {
    int bid   = blockIdx.x;
    int chunk = bid & (CHUNKS - 1);
    int t     = bid >> 3;
    int ow    = t % OW; t /= OW;
    int oh    = t % OH; t /= OH;
    int b     = t;

    int tid = threadIdx.x;
    int g   = tid & (G - 1);
    int r   = tid >> 6;

    int row  = oh * WIN + chunk * ROWS_PER_CHUNK + r;
    int col0 = ow * WIN;

    const float4* p = reinterpret_cast<const float4*>(
        x + (((size_t)b * H + row) * W + col0) * C) + g;

    float4 acc = make_float4(0.f, 0.f, 0.f, 0.f);
#pragma unroll
    for (int c = 0; c < WIN; ++c) {
        float4 v = p[(size_t)c * G];
        acc.x += v.x; acc.y += v.y; acc.z += v.z; acc.w += v.w;
    }

    __shared__ float4 lds[ROWS_PER_CHUNK][G];
    lds[r][g] = acc;
    __syncthreads();

    if (r == 0) {
        float4 a0 = lds[0][g];
        float4 a1 = lds[1][g];
        float4 a2 = lds[2][g];
        float4 a3 = lds[3][g];
        const float s = 1.0f / (float)(WIN * WIN);
        float* o = out + (size_t)(bid >> 3) * C + g * 4;
        atomicAdd(o + 0, (a0.x + a1.x + a2.x + a3.x) * s);
        atomicAdd(o + 1, (a0.y + a1.y + a2.y + a3.y) * s);
        atomicAdd(o + 2, (a0.z + a1.z + a2.z + a3.z) * s);
        atomicAdd(o + 3, (a0.w + a1.w + a2.w + a3.w) * s);
    }
}

extern "C" void kernel_launch(void* const* d_in, const int* in_sizes, int n_in,
                              void* d_out, int out_size, void* d_ws, size_t ws_size,
                              hipStream_t stream) {
    const float* x = (const float*)d_in[0];
    float* out = (float*)d_out;

    if (ws_size >= WS_NEEDED) {
        float* ws = (float*)d_ws;
        pool_partial_kernel<<<NCHUNK_BLOCKS, 256, 0, stream>>>(x, ws);
        reduce_kernel<<<(OUT_ELEMS + 255) / 256, 256, 0, stream>>>(ws, out);
    } else {
        zero_out_kernel<<<(OUT_ELEMS + 255) / 256, 256, 0, stream>>>(out, OUT_ELEMS);
        pool_atomic_kernel<<<NCHUNK_BLOCKS, 256, 0, stream>>>(x, out);
    }
}